// Round 11
// baseline (328.744 us; speedup 1.0000x reference)
//
#include <hip/hip_runtime.h>
#include <cstddef>
#include <cstdint>

#define BATCH 32

// All intermediates are NODE-MAJOR: X[n][b][f]  (addr = (n*32 + b)*F + f).
// Workspace (floats):
//   Xt : 1,572,864   (transposed input, [16384][32][3])
//   T  : 20,971,520  (T1..T5; max slice = layer1: 4096*32*32 = 4,194,304)
//   X1 : 4,194,304   ([4096][32][32])
//   X2 : 1,048,576   ([1024][32][32])
//   X3 : 262,144     ([256][32][32])
//   X4 : 131,072     ([32][4096] batch-major for encoder)
//   P  : 65,536      (encoder split-K partials)

__device__ __forceinline__ void fma4(float4& a, float s, const float4& w) {
  a.x += s * w.x; a.y += s * w.y; a.z += s * w.z; a.w += s * w.w;
}
__device__ __forceinline__ float4 relu4(const float4& a) {
  return make_float4(fmaxf(a.x, 0.f), fmaxf(a.y, 0.f), fmaxf(a.z, 0.f), fmaxf(a.w, 0.f));
}

// ---------------- transpose x[b][n][3] -> Xt[n][b][3] ----------------
__global__ void __launch_bounds__(256) transpose_x(
    const float* __restrict__ x, float* __restrict__ xt)
{
  int t = blockIdx.x * 256 + threadIdx.x;     // n*96 + b*3 + f
  int n = t / 96;
  int r = t % 96;
  int b = r / 3;
  int f = r - b * 3;
  xt[t] = x[((size_t)b * 16384 + n) * 3 + f];
}

// ---------------- node-major Cheb step (layer 0 only) ----------------
template<int N, int R4>
__global__ void __launch_bounds__(256) cheb_step_nm(
    const float4* __restrict__ Tin, const float4* __restrict__ Tpp,
    const int* __restrict__ ec, float4* __restrict__ Tout,
    float coef, float beta)
{
  int idx = blockIdx.x * 256 + threadIdx.x;   // exact grid: N*R4 threads
  int n = idx / R4;
  int r = idx % R4;
  const int* e = ec + n * 6;
  float4 s = make_float4(0.f, 0.f, 0.f, 0.f);
#pragma unroll
  for (int d = 0; d < 6; ++d) {
    float4 v = Tin[(size_t)e[d] * R4 + r];
    s.x += v.x; s.y += v.y; s.z += v.z; s.w += v.w;
  }
  float4 p = Tpp[idx];
  float4 o;
  o.x = coef * s.x + beta * p.x;
  o.y = coef * s.y + beta * p.y;
  o.z = coef * s.z + beta * p.z;
  o.w = coef * s.w + beta * p.w;
  Tout[idx] = o;
}

// ---------------- LDS-resident Chebyshev recurrence v4 (layers 1-3) ----------------
// Block = (b, f-slab of FS=2). One LDS buffer holds T_{k-1}[all n][FS];
// T_{k-2} in registers. ec for the thread's OWNED nodes is preloaded into
// registers ONCE (identical across all 5 steps) -- removes the 200-900 cyc
// global ec reload from the per-step dependent chain (R10's limiter).
template<int N, int F, int THREADS, int MINW>
__global__ void __launch_bounds__(THREADS, MINW) cheb_recur_reg(
    const float* __restrict__ X,    // node-major [N][32][F]
    const int* __restrict__ ec,     // [N][6]
    float* __restrict__ T)          // 5 slices, node-major
{
  constexpr int FS = 2;
  constexpr int NPT = N / THREADS;             // nodes per thread
  __shared__ float cur[N * FS];
  const float cI = -1.0f / 6.0f;
  const float cS = -1.0f / 3.0f;
  const int b = blockIdx.x & 31;
  const int fbase = (blockIdx.x >> 5) * FS;
  constexpr size_t SL = (size_t)N * 32 * F;    // slice stride (floats)
  float prevv[NPT][FS];                        // T_{k-2} at owned nodes
  int en[NPT][6];                              // preloaded edge indices
  // load T0 slab + edge indices (once)
#pragma unroll
  for (int i = 0; i < NPT; ++i) {
    int n = threadIdx.x + i * THREADS;
    float2 v = *(const float2*)(X + ((size_t)n * 32 + b) * F + fbase);
    cur[n * FS + 0] = v.x;
    cur[n * FS + 1] = v.y;
    const int* e = ec + n * 6;
#pragma unroll
    for (int d = 0; d < 6; ++d) en[i][d] = e[d];
  }
  __syncthreads();
#pragma unroll 1
  for (int k = 1; k <= 5; ++k) {
    float newv[NPT][FS];
    float* Tk = T + (size_t)(k - 1) * SL;
#pragma unroll
    for (int i = 0; i < NPT; ++i) {
      int n = threadIdx.x + i * THREADS;
      float s0 = 0.f, s1 = 0.f;
#pragma unroll
      for (int d = 0; d < 6; ++d) {
        int c = en[i][d];
        s0 += cur[c * FS + 0];
        s1 += cur[c * FS + 1];
      }
      float v0, v1;
      if (k == 1) { v0 = cI * s0; v1 = cI * s1; }
      else        { v0 = cS * s0 - prevv[i][0]; v1 = cS * s1 - prevv[i][1]; }
      newv[i][0] = v0; newv[i][1] = v1;
      *(float2*)(Tk + ((size_t)n * 32 + b) * F + fbase) = make_float2(v0, v1);
    }
    __syncthreads();   // all gathers of T_{k-1} complete
#pragma unroll
    for (int i = 0; i < NPT; ++i) {
      int n = threadIdx.x + i * THREADS;
      prevv[i][0] = cur[n * FS + 0];           // own slot still = T_{k-1}
      prevv[i][1] = cur[n * FS + 1];
      cur[n * FS + 0] = newv[i][0];            // T_k -> cur
      cur[n * FS + 1] = newv[i][1];
    }
    __syncthreads();
  }
}

// ---------------- fused pool(relu(conv)), FIN=3, materialized T1..T5 ----------------
template<int N, int M, int FOUT, bool OUT_BM>
__global__ void __launch_bounds__(256) pool_conv_f3(
    const float* __restrict__ X, const float* __restrict__ T,
    const float* __restrict__ W, const float* __restrict__ bias,
    const int* __restrict__ pc, const float* __restrict__ pv,
    float* __restrict__ out)
{
  constexpr int F4 = FOUT / 4;
  constexpr size_t SL = (size_t)N * BATCH * 3;   // slice stride (floats)
  __shared__ float Ws[6 * 3 * FOUT];
  for (int i = threadIdx.x; i < 6 * 3 * FOUT; i += 256) Ws[i] = W[i];
  __syncthreads();
  const float4* Ws4 = (const float4*)Ws;
  int t = blockIdx.x * 256 + threadIdx.x;     // exact grid: M*32*F4
  int fo4 = t % F4;
  int b   = (t / F4) % BATCH;
  int m   = t / (F4 * BATCH);
  int c0 = pc[m * 3 + 0], c1 = pc[m * 3 + 1], c2 = pc[m * 3 + 2];
  float v0 = pv[m * 3 + 0], v1 = pv[m * 3 + 1], v2 = pv[m * 3 + 2];
  float4 bi = ((const float4*)bias)[fo4];
  float4 a0 = bi, a1 = bi, a2 = bi;
#pragma unroll
  for (int k = 0; k < 6; ++k) {
    const float* base = (k == 0) ? X : (T + (size_t)(k - 1) * SL);
    const float* r0 = base + ((size_t)c0 * BATCH + b) * 3;
    const float* r1 = base + ((size_t)c1 * BATCH + b) * 3;
    const float* r2 = base + ((size_t)c2 * BATCH + b) * 3;
#pragma unroll
    for (int f = 0; f < 3; ++f) {
      float4 w = Ws4[(k * 3 + f) * F4 + fo4];
      fma4(a0, r0[f], w);
      fma4(a1, r1[f], w);
      fma4(a2, r2[f], w);
    }
  }
  a0 = relu4(a0); a1 = relu4(a1); a2 = relu4(a2);
  float4 acc;
  acc.x = v0*a0.x + v1*a1.x + v2*a2.x;
  acc.y = v0*a0.y + v1*a1.y + v2*a2.y;
  acc.z = v0*a0.z + v1*a1.z + v2*a2.z;
  acc.w = v0*a0.w + v1*a1.w + v2*a2.w;
  size_t oi = OUT_BM ? (((size_t)b * M + m) * F4 + fo4) : (((size_t)m * BATCH + b) * F4 + fo4);
  ((float4*)out)[oi] = acc;
}

// ---------------- fused pool(relu(conv)), FIN=32, node-major T ----------------
template<int N, int M, int FOUT, bool OUT_BM>
__global__ void __launch_bounds__(256) pool_conv_v32(
    const float* __restrict__ X, const float* __restrict__ T,
    const float* __restrict__ W, const float* __restrict__ bias,
    const int* __restrict__ pc, const float* __restrict__ pv,
    float* __restrict__ out)
{
  constexpr int FIN = 32;
  constexpr int F4 = FOUT / 4;
  constexpr size_t SL4 = (size_t)N * BATCH * FIN / 4;   // slice stride (float4)
  __shared__ float Ws[6 * FIN * FOUT];                  // 24 KB or 48 KB
  for (int i = threadIdx.x; i < 6 * FIN * FOUT; i += 256) Ws[i] = W[i];
  __syncthreads();
  const float4* Ws4 = (const float4*)Ws;
  const float4* X4p = (const float4*)X;
  const float4* T4s = (const float4*)T;
  int t = blockIdx.x * 256 + threadIdx.x;     // exact grid: M*32*F4
  int fo4 = t % F4;
  int b   = (t / F4) % BATCH;
  int m   = t / (F4 * BATCH);
  int c0 = pc[m * 3 + 0], c1 = pc[m * 3 + 1], c2 = pc[m * 3 + 2];
  float v0 = pv[m * 3 + 0], v1 = pv[m * 3 + 1], v2 = pv[m * 3 + 2];
  float4 bi = ((const float4*)bias)[fo4];
  float4 a0 = bi, a1 = bi, a2 = bi;
#pragma unroll 1
  for (int k = 0; k < 6; ++k) {
    const float4* base = (k == 0) ? X4p : (T4s + (size_t)(k - 1) * SL4);
    const float4* r0 = base + ((size_t)c0 * BATCH + b) * 8;
    const float4* r1 = base + ((size_t)c1 * BATCH + b) * 8;
    const float4* r2 = base + ((size_t)c2 * BATCH + b) * 8;
#pragma unroll
    for (int fi = 0; fi < 8; ++fi) {
      float4 t0 = r0[fi], t1 = r1[fi], t2 = r2[fi];
#pragma unroll
      for (int ff = 0; ff < 4; ++ff) {
        float4 w = Ws4[((k * 32) + fi * 4 + ff) * F4 + fo4];
        fma4(a0, ((const float*)&t0)[ff], w);
        fma4(a1, ((const float*)&t1)[ff], w);
        fma4(a2, ((const float*)&t2)[ff], w);
      }
    }
  }
  a0 = relu4(a0); a1 = relu4(a1); a2 = relu4(a2);
  float4 acc;
  acc.x = v0*a0.x + v1*a1.x + v2*a2.x;
  acc.y = v0*a0.y + v1*a1.y + v2*a2.y;
  acc.z = v0*a0.z + v1*a1.z + v2*a2.z;
  acc.w = v0*a0.w + v1*a1.w + v2*a2.w;
  size_t oi = OUT_BM ? (((size_t)b * M + m) * F4 + fo4) : (((size_t)m * BATCH + b) * F4 + fo4);
  ((float4*)out)[oi] = acc;
}

// ---------------- encoder split-K partial ----------------
__global__ void __launch_bounds__(256) encoder_partial(
    const float* __restrict__ Xf, const float* __restrict__ encW,
    float* __restrict__ partial)
{
  int b  = blockIdx.x;        // 0..31
  int ks = blockIdx.y;        // 0..15
  int fo = threadIdx.x & 127;
  int half = threadIdx.x >> 7;
  const float* xr = Xf + b * 4096 + ks * 256 + half * 128;
  const float* w  = encW + (size_t)(ks * 256 + half * 128) * 128;
  float acc = 0.f;
#pragma unroll 8
  for (int i = 0; i < 128; ++i) acc += xr[i] * w[(size_t)i * 128 + fo];
  __shared__ float part[256];
  part[threadIdx.x] = acc;
  __syncthreads();
  if (half == 0) partial[(size_t)(b * 16 + ks) * 128 + fo] = part[fo] + part[128 + fo];
}

// ---------------- fused encoder-reduce + relu + classifier ----------------
__global__ void __launch_bounds__(128) encoder_reduce_cls(
    const float* __restrict__ partial, const float* __restrict__ encB,
    const float* __restrict__ clsW, const float* __restrict__ clsB,
    float* __restrict__ out)
{
  int b = blockIdx.x;           // 0..31
  int fo = threadIdx.x;         // 0..127
  float acc = encB[fo];
#pragma unroll
  for (int ks = 0; ks < 16; ++ks) acc += partial[(size_t)(b * 16 + ks) * 128 + fo];
  __shared__ float Hs[128];
  Hs[fo] = fmaxf(acc, 0.f);
  __syncthreads();
  if (fo < 10) {
    float s = clsB[fo];
#pragma unroll 4
    for (int f = 0; f < 128; ++f) s += Hs[f] * clsW[f * 10 + fo];
    out[b * 10 + fo] = s;
  }
}

extern "C" void kernel_launch(void* const* d_in, const int* in_sizes, int n_in,
                              void* d_out, int out_size, void* d_ws, size_t ws_size,
                              hipStream_t stream)
{
  const float* x   = (const float*)d_in[0];
  const int* ec0 = (const int*)d_in[2];
  const int* ec1 = (const int*)d_in[4];
  const int* ec2 = (const int*)d_in[6];
  const int* ec3 = (const int*)d_in[8];
  const int* pc0 = (const int*)d_in[10]; const float* pv0 = (const float*)d_in[11];
  const int* pc1 = (const int*)d_in[13]; const float* pv1 = (const float*)d_in[14];
  const int* pc2 = (const int*)d_in[16]; const float* pv2 = (const float*)d_in[17];
  const int* pc3 = (const int*)d_in[19]; const float* pv3 = (const float*)d_in[20];
  const float* W0 = (const float*)d_in[21]; const float* b0 = (const float*)d_in[22];
  const float* W1 = (const float*)d_in[23]; const float* b1 = (const float*)d_in[24];
  const float* W2 = (const float*)d_in[25]; const float* b2 = (const float*)d_in[26];
  const float* W3 = (const float*)d_in[27]; const float* b3 = (const float*)d_in[28];
  const float* encW = (const float*)d_in[29]; const float* encB = (const float*)d_in[30];
  const float* clsW = (const float*)d_in[31]; const float* clsB = (const float*)d_in[32];
  float* out = (float*)d_out;

  float* ws = (float*)d_ws;
  float* Xt = ws;                       // 1,572,864
  float* T  = Xt + 1572864;             // 20,971,520 (T1..T5, layer-1 sized)
  float* X1 = T  + 20971520;            // 4,194,304
  float* X2 = X1 + 4194304;             // 1,048,576
  float* X3 = X2 + 1048576;             // 262,144
  float* X4 = X3 + 262144;              // 131,072  ([32][4096])
  float* P  = X4 + 131072;              // 65,536

  const float cI = -1.0f / 6.0f;
  const float cS = -1.0f / 3.0f;
  dim3 blk(256);

  transpose_x<<<dim3(6144), blk, 0, stream>>>(x, Xt);

  // ================= layer 0: N=16384, R=96 (R4=24), M=4096 =================
  {
    constexpr size_t S = (size_t)16384 * 96;   // slice floats
    const float4* Xt4 = (const float4*)Xt;
    cheb_step_nm<16384, 24><<<dim3(1536), blk, 0, stream>>>(
        Xt4, Xt4, ec0, (float4*)T, cI, 0.f);
    cheb_step_nm<16384, 24><<<dim3(1536), blk, 0, stream>>>(
        (const float4*)T, Xt4, ec0, (float4*)(T + S), cS, -1.f);
    cheb_step_nm<16384, 24><<<dim3(1536), blk, 0, stream>>>(
        (const float4*)(T + S), (const float4*)T, ec0, (float4*)(T + 2 * S), cS, -1.f);
    cheb_step_nm<16384, 24><<<dim3(1536), blk, 0, stream>>>(
        (const float4*)(T + 2 * S), (const float4*)(T + S), ec0, (float4*)(T + 3 * S), cS, -1.f);
    cheb_step_nm<16384, 24><<<dim3(1536), blk, 0, stream>>>(
        (const float4*)(T + 3 * S), (const float4*)(T + 2 * S), ec0, (float4*)(T + 4 * S), cS, -1.f);
    pool_conv_f3<16384, 4096, 32, false><<<dim3(4096), blk, 0, stream>>>(
        Xt, T, W0, b0, pc0, pv0, X1);
  }
  // ================= layer 1: N=4096, F=32, M=1024 =================
  // 512 blocks (32 b x 16 slabs) x 1024 thr (NPT=4): ec preloaded (24 regs),
  // ~55 VGPR -> 2 blocks/CU = 32 waves/CU if <=64; 32 KB LDS.
  {
    cheb_recur_reg<4096, 32, 1024, 4><<<dim3(512), dim3(1024), 0, stream>>>(X1, ec1, T);
    pool_conv_v32<4096, 1024, 32, false><<<dim3(1024), blk, 0, stream>>>(
        X1, T, W1, b1, pc1, pv1, X2);
  }
  // ================= layer 2: N=1024, F=32, M=256 =================
  {
    cheb_recur_reg<1024, 32, 512, 4><<<dim3(512), dim3(512), 0, stream>>>(X2, ec2, T);
    pool_conv_v32<1024, 256, 32, false><<<dim3(256), blk, 0, stream>>>(
        X2, T, W2, b2, pc2, pv2, X3);
  }
  // ================= layer 3: N=256, F=32, M=64, FOUT=64, batch-major out =================
  {
    cheb_recur_reg<256, 32, 256, 4><<<dim3(512), blk, 0, stream>>>(X3, ec3, T);
    pool_conv_v32<256, 64, 64, true><<<dim3(128), blk, 0, stream>>>(
        X3, T, W3, b3, pc3, pv3, X4);
  }
  // ================= head =================
  encoder_partial<<<dim3(32, 16), blk, 0, stream>>>(X4, encW, P);
  encoder_reduce_cls<<<dim3(32), dim3(128), 0, stream>>>(P, encB, clsW, clsB, out);
}